// Round 9
// baseline (228.370 us; speedup 1.0000x reference)
//
#include <hip/hip_runtime.h>
#include <math.h>

// ConvSlimCapsule3D, round 13: r12 skeleton, barrier/LDS-diet on caps.
//  - epilogue uses swapped MFMA (r11-verified): D row = channel -> vote writes are
//    16x ds_write_b64 per thread (was 64x ds_write_b16, 4.78M conflict cycles).
//  - routing remapped to (oo=t&7, half=bit3, vv=t>>4): softmax over o = 8-lane DPP
//    sum8 (r10-proven), half-combine = DPP row_ror:8. Routing loop has ZERO LDS and
//    ZERO barriers (was 4 barriers + LG/RT round-trips).
//  - output bounced through 16.6KB LDS tile (overlays dead votes) for coalesced
//    128B stores. Barriers per block: 8 -> 5.
//  - prep_all unchanged from r12 (passed).

typedef _Float16 half8 __attribute__((ext_vector_type(8)));
typedef _Float16 half4 __attribute__((ext_vector_type(4)));
typedef float f32x4 __attribute__((ext_vector_type(4)));
typedef float f32x2 __attribute__((ext_vector_type(2)));

__device__ __forceinline__ void gload_lds16(const void* g, void* l) {
    __builtin_amdgcn_global_load_lds(
        (const __attribute__((address_space(1))) void*)g,
        (__attribute__((address_space(3))) void*)l, 16, 0, 0);
}

template <int CTRL>
__device__ __forceinline__ float dppf(float x) {
    return __builtin_bit_cast(float, __builtin_amdgcn_update_dpp(
        0, __builtin_bit_cast(int, x), CTRL, 0xF, 0xF, true));
}
// sum across each aligned 8-lane group (VALU only; r10-proven trio)
__device__ __forceinline__ float sum8(float x) {
    x += dppf<0xB1>(x);    // quad_perm(1,0,3,2): ^1
    x += dppf<0x4E>(x);    // quad_perm(2,3,0,1): ^2
    x += dppf<0x141>(x);   // row_half_mirror: completes the 8-group
    return x;
}
// lane^8 exchange (row_ror:8 within 16-lane row)
__device__ __forceinline__ float ror8f(float x) { return dppf<0x128>(x); }

// ---- prep_all: 744 blocks x 256 threads (r12, unchanged) ----
__global__ __launch_bounds__(256) void prep_all(const float* __restrict__ x,
                                                const float* __restrict__ cw,
                                                _Float16* __restrict__ xt,
                                                _Float16* __restrict__ wh2) {
    __shared__ _Float16 lds[272 * 136];   // 73,984 B (interior blocks only)
    const int t   = threadIdx.x;
    const int bid = blockIdx.x;

    if (bid < 256) {
        const int b  = bid >> 7;
        const int z  = (bid >> 2) & 31;
        const int y0 = (bid & 3) << 3;
        {
            const int rw = t >> 4, u = t & 15;
            const int y = rw >> 1, wp = (rw & 1) * 33;
            *(half8*)&lds[(y * 34 + wp) * 136 + u * 8] = (half8)(_Float16)0.f;
        }
        const float* xb = x + (size_t)b * 4194304 + z * 1024 + y0 * 32;
        #pragma unroll 4
        for (int i = 0; i < 32; i++) {
            const int idx4 = i * 256 + t;          // 0..8191
            const int ch = idx4 >> 6;              // 0..127
            const int y  = (idx4 >> 3) & 7;
            const int w4 = idx4 & 7;
            const f32x4 v = *(const f32x4*)(xb + (size_t)ch * 32768 + y * 32 + w4 * 4);
            const int rbase = y * 34 + w4 * 4 + 1;
            #pragma unroll
            for (int e = 0; e < 4; e++)
                lds[(rbase + e) * 136 + ch] = (_Float16)v[e];
        }
        __syncthreads();
        _Float16* dst = xt + ((size_t)((b * 34 + z + 1) * 34 + y0 + 1)) * 34 * 128;
        #pragma unroll
        for (int k = 0; k < 17; k++) {
            const int idx = k * 256 + t;
            const int vox = idx >> 4, u = idx & 15;
            *(half8*)(dst + (size_t)vox * 128 + u * 8) =
                *(const half8*)&lds[vox * 136 + u * 8];
        }
        return;
    }
    if (bid < 520) {
        const int rid = bid - 256;
        const int b = rid / 132, rr = rid - b * 132;
        int zp, yp;
        if (rr < 68) { zp = (rr >= 34) ? 33 : 0; yp = rr % 34; }
        else { const int r2 = rr - 68; zp = 1 + (r2 >> 1); yp = (r2 & 1) ? 33 : 0; }
        _Float16* dst = xt + ((size_t)((b * 34 + zp) * 34 + yp)) * 34 * 128;
        const half8 z8 = (half8)(_Float16)0.f;
        for (int idx = t; idx < 544; idx += 256)
            *(half8*)(dst + idx * 8) = z8;
        return;
    }
    {
        const int idx = (bid - 520) * 256 + t;
        const int n   = idx / 448;
        const int rem = idx - n * 448;
        const int c   = rem >> 5;
        const int k   = rem & 31;
        const int tp  = k >> 4, ca = k & 15;
        const int tap = 2 * c + tp;
        float v = (tap < 27) ? cw[n * 432 + ca * 27 + tap] : 0.0f;
        wh2[c * 4096 + n * 32 + k] = (_Float16)v;
    }
}

// =================== fused caps kernel =========================================
__global__ __launch_bounds__(512, 4) void caps_mfma_kernel(
    const _Float16* __restrict__ xt,  // (2,34,34,34,128) f16 padded
    const _Float16* __restrict__ wh2, // (14,128,32) f16 reordered
    const float* __restrict__ cb,     // (128,)
    const float* __restrict__ bias,   // (8,16)
    float* __restrict__ out)          // (2,8,16,32,32,32) f32
{
    // 78,848 B: slab = 306 live rows + 2 phantom, x 256B.
    // Votes (66,048B) overlay slab after B1; OF (32x130 f32) overlays after B3.
    __shared__ half8 slabv[4928];
    char* smem = (char*)slabv;
    _Float16* Vh = (_Float16*)slabv;
    float* OF = (float*)slabv;        // [vox 32][ch, stride 130] f32 = 16,640 B

    const int t  = threadIdx.x;
    const int bx = blockIdx.x;
    const int gid = ((bx & 7) << 8) | (bx >> 3);   // XCD-contiguous (2048 = 8*256)
    const int h = gid & 31;
    const int d = (gid >> 5) & 31;
    const int b = gid >> 10;

    const int wid = t >> 6, lane = t & 63;

    // stage slab: 308 rows x 256B via global_load_lds
    {
        const int lrow = lane >> 4;
        const int s    = lane & 15;
        const int bzd  = b * 34 + d;
        for (int i = wid; i < 77; i += 8) {
            const int rr0 = i << 2;
            const int rr  = rr0 + lrow;
            int zy = rr / 34;
            int j  = rr - zy * 34;
            if (rr >= 306) { zy = 0; j = 0; }
            const int dz  = (zy * 11) >> 5;
            const int dy  = zy - dz * 3;
            const int uu  = s ^ (j & 15);
            const unsigned off =
                ((((unsigned)(bzd + dz) * 34u + (unsigned)(h + dy)) * 34u
                  + (unsigned)j) << 8) + (unsigned)(uu << 4);
            gload_lds16((const char*)xt + off, smem + (rr0 << 8));
        }
    }
    __syncthreads();   // B0: slab staged

    // GEMM (swapped operands, r11-verified): D row = ch, D col = voxel.
    const int q = lane >> 4, r = lane & 15;
    const int qlow = q & 1, tphase = q >> 1;

    int zyA[14], dxA[14];
    #pragma unroll
    for (int c = 0; c < 14; c++) {
        int tap = 2 * c + tphase;
        if (tap > 26) tap = 0;             // tap27: weight k-slots are zero
        const int dz = tap / 9, r9 = tap - dz * 9;
        const int dy = r9 / 3,  dxx = r9 - dy * 3;
        zyA[c] = dz * 3 + dy;
        dxA[c] = dxx;
    }
    const int uA = wid * 2 + qlow;
    const _Float16* bp0 = wh2 + r * 32 + q * 8;
    const _Float16* bp1 = bp0 + 2048;

    f32x4 acc[2][8];                       // [vt voxel-half][nt channel-tile]
    #pragma unroll
    for (int i = 0; i < 2; i++)
        #pragma unroll
        for (int j = 0; j < 8; j++) acc[i][j] = (f32x4)0.f;

    #pragma unroll
    for (int c = 0; c < 14; c++) {
        half8 bf[8];
        #pragma unroll
        for (int nt = 0; nt < 4; nt++) {
            bf[nt]     = *(const half8*)(bp0 + c * 4096 + nt * 512);
            bf[nt + 4] = *(const half8*)(bp1 + c * 4096 + nt * 512);
        }
        const int jw = r + dxA[c];
        const int js = jw & 15;
        const char* abase = smem + zyA[c] * 8704 + jw * 256 + ((uA ^ js) << 4);
        const half8 af0 = *(const half8*)abase;
        const half8 af1 = *(const half8*)(abase + 4096);
        #pragma unroll
        for (int nt = 0; nt < 8; nt++) {
            acc[0][nt] = __builtin_amdgcn_mfma_f32_16x16x32_f16(bf[nt], af0,
                                                                acc[0][nt], 0, 0, 0);
            acc[1][nt] = __builtin_amdgcn_mfma_f32_16x16x32_f16(bf[nt], af1,
                                                                acc[1][nt], 0, 0, 0);
        }
    }

    __syncthreads();   // B1: slab reads done -> votes overlay

    // epilogue: 4 contiguous channels per fragment -> one ds_write_b64 each
    f32x4 cbq[8];
    #pragma unroll
    for (int nt = 0; nt < 8; nt++)
        cbq[nt] = *(const f32x4*)&cb[nt * 16 + q * 4];
    #pragma unroll
    for (int vt = 0; vt < 2; vt++) {
        _Float16* vp = &Vh[(vt * 16 + r) * 1032 + wid * 128 + q * 4];
        #pragma unroll
        for (int nt = 0; nt < 8; nt++) {
            half4 hv;
            #pragma unroll
            for (int e = 0; e < 4; e++)
                hv[e] = (_Float16)(acc[vt][nt][e] + cbq[nt][e]);
            *(half4*)(vp + nt * 16) = hv;
        }
    }
    __syncthreads();   // B2: vote writes visible

    // ============ routing: (oo = t&7, half = bit3, vv = t>>4) — barrier-free ======
    const int oo   = t & 7;
    const int half = (t >> 3) & 1;
    const int vv   = t >> 4;              // voxel 0..31
    const int ib   = half << 2;           // own in_dims ib..ib+3

    f32x2 vf2[4][8];                      // [own i][atom pair] (all 16 atoms)
    #pragma unroll
    for (int ii = 0; ii < 4; ii++) {
        #pragma unroll
        for (int ah = 0; ah < 2; ah++) {
            const half8 hv =
                *(const half8*)&Vh[vv * 1032 + (ib + ii) * 128 + oo * 16 + ah * 8];
            #pragma unroll
            for (int k = 0; k < 4; k++) {
                f32x2 e; e[0] = (float)hv[2 * k]; e[1] = (float)hv[2 * k + 1];
                vf2[ii][ah * 4 + k] = e;
            }
        }
    }
    __syncthreads();   // B3: vote reads done -> OF may overlay vote region

    float vn[4];
    #pragma unroll
    for (int ii = 0; ii < 4; ii++) {
        f32x2 s = (f32x2)0.f;
        #pragma unroll
        for (int k = 0; k < 8; k++)
            s = __builtin_elementwise_fma(vf2[ii][k], vf2[ii][k], s);
        vn[ii] = sqrtf(s[0] + s[1]);
    }
    f32x2 bl2[8];
    #pragma unroll
    for (int k = 0; k < 8; k++)
        bl2[k] = *(const f32x2*)&bias[oo * 16 + 2 * k];

    float rt[4], lgr[4];
    #pragma unroll
    for (int ii = 0; ii < 4; ii++) { rt[ii] = 0.125f; lgr[ii] = 0.f; }
    f32x2 pre2[8];

    for (int it = 0; it < 3; it++) {
        #pragma unroll
        for (int k = 0; k < 8; k++) pre2[k] = (f32x2)0.f;
        #pragma unroll
        for (int ii = 0; ii < 4; ii++) {
            f32x2 rtv; rtv[0] = rt[ii]; rtv[1] = rt[ii];
            #pragma unroll
            for (int k = 0; k < 8; k++)
                pre2[k] = __builtin_elementwise_fma(rtv, vf2[ii][k], pre2[k]);
        }
        #pragma unroll
        for (int k = 0; k < 8; k++) {      // combine i-halves via lane^8 (VALU DPP)
            f32x2 cmb;
            cmb[0] = pre2[k][0] + ror8f(pre2[k][0]);
            cmb[1] = pre2[k][1] + ror8f(pre2[k][1]);
            pre2[k] = bl2[k] + cmb;
        }
        if (it == 2) break;

        f32x2 s2v = (f32x2)0.f;
        #pragma unroll
        for (int k = 0; k < 8; k++)
            s2v = __builtin_elementwise_fma(pre2[k], pre2[k], s2v);
        const float pn = sqrtf(s2v[0] + s2v[1]);

        #pragma unroll
        for (int ii = 0; ii < 4; ii++) {
            f32x2 dv = (f32x2)0.f;
            #pragma unroll
            for (int k = 0; k < 8; k++)
                dv = __builtin_elementwise_fma(pre2[k], vf2[ii][k], dv);
            lgr[ii] += __fdividef(dv[0] + dv[1], fmaxf(pn * vn[ii], 1e-8f));
            const float ex = __expf(lgr[ii]);   // |lgr| <= 2, no max-sub needed
            rt[ii] = __fdividef(ex, sum8(ex));  // softmax over o: 8-lane DPP
        }
    }

    // squash -> OF[vox][ch] (stride 130), then coalesced store
    f32x2 s2v = (f32x2)0.f;
    #pragma unroll
    for (int k = 0; k < 8; k++)
        s2v = __builtin_elementwise_fma(pre2[k], pre2[k], s2v);
    const float n2 = s2v[0] + s2v[1];
    const float nn = sqrtf(n2);
    const float scale = __fdividef(n2, (1.f + n2) * (nn + 1e-12f));
    #pragma unroll
    for (int a = 0; a < 8; a++) {
        const float pv = half ? pre2[4 + (a >> 1)][a & 1]    // atoms 8..15
                              : pre2[(a >> 1)][a & 1];       // atoms 0..7
        OF[vv * 130 + oo * 16 + half * 8 + a] = pv * scale;
    }
    __syncthreads();   // B4: OF complete

    {
        const int ch = t >> 2, sg = t & 3;    // ch 0..127, w-segment 0..3
        f32x4 o0, o1;
        #pragma unroll
        for (int e = 0; e < 4; e++) o0[e] = OF[(sg * 8 + e) * 130 + ch];
        #pragma unroll
        for (int e = 0; e < 4; e++) o1[e] = OF[(sg * 8 + 4 + e) * 130 + ch];
        float* op = out + ((size_t)((b * 8 + (ch >> 4)) * 16 + (ch & 15))) * 32768
                        + d * 1024 + h * 32 + sg * 8;
        *(f32x4*)op = o0;
        *(f32x4*)(op + 4) = o1;
    }
}

extern "C" void kernel_launch(void* const* d_in, const int* in_sizes, int n_in,
                              void* d_out, int out_size, void* d_ws, size_t ws_size,
                              hipStream_t stream) {
    const float* x    = (const float*)d_in[0];
    const float* cw   = (const float*)d_in[1];
    const float* cb   = (const float*)d_in[2];
    const float* bias = (const float*)d_in[3];
    float* out = (float*)d_out;
    _Float16* wh2 = (_Float16*)d_ws;                     // 114,688 B
    _Float16* xt  = (_Float16*)((char*)d_ws + 114688);   // 20,123,648 B

    hipLaunchKernelGGL(prep_all, dim3(744), dim3(256), 0, stream, x, cw, xt, wh2);
    hipLaunchKernelGGL(caps_mfma_kernel, dim3(2048), dim3(512), 0, stream,
                       xt, wh2, cb, bias, out);
}